// Round 3
// baseline (464.894 us; speedup 1.0000x reference)
//
#include <hip/hip_runtime.h>

#define V1n 40962
#define V2n 163842
#define Bn  4
#define T2S 163848   // padded t2 row stride (16B-aligned rows)

typedef _Float16 h8   __attribute__((ext_vector_type(8)));
typedef _Float16 h2   __attribute__((ext_vector_type(2)));
typedef float    f32x4 __attribute__((ext_vector_type(4)));

__device__ __forceinline__ float h2f(_Float16 h) { return (float)h; }

// ---------------- K0: pack Wup into fp16 MFMA B-fragment layout (unchanged)
__global__ __launch_bounds__(256) void k_pack_up(const float* __restrict__ Wup,
                                                 _Float16* __restrict__ WupP) {
  int i = blockIdx.x * 256 + threadIdx.x;
  if (i >= 14336) return;
  int e = i & 7, col = (i >> 3) & 15, g = i >> 7;   // g = (kt*4+quad)*14 + nt
  int nt = g % 14, kq = g / 14;
  int j = nt * 16 + col;
  int k = (kq >> 2) * 32 + (kq & 3) * 8 + e;
  WupP[i] = (_Float16)Wup[j * 64 + k];
}

// ---------------- K1: upconv GEMM. Block = 16 vertices x 4 batches (one wave per batch).
__global__ __launch_bounds__(256, 4) void k_upconv(const float* __restrict__ x1,
    const float* __restrict__ bup, const _Float16* __restrict__ WupP,
    _Float16* __restrict__ rawq) {
  int lane = threadIdx.x & 63, wv = threadIdx.x >> 6;   // wv = batch
  int col = lane & 15, quad = lane >> 4;
  int v0 = blockIdx.x * 16;
  int v = v0 + col;
  int vc = min(v, V1n - 1);
  const float* xb = x1 + ((size_t)wv * 64) * V1n + vc;
  h8 a0, a1;
#pragma unroll
  for (int e = 0; e < 8; ++e) a0[e] = (_Float16)xb[(size_t)(quad * 8 + e) * V1n];
#pragma unroll
  for (int e = 0; e < 8; ++e) a1[e] = (_Float16)xb[(size_t)(32 + quad * 8 + e) * V1n];
  f32x4 acc[14];
#pragma unroll
  for (int nt = 0; nt < 14; ++nt) {
    float bv = bup[nt * 16 + col];
    acc[nt] = (f32x4){bv, bv, bv, bv};
  }
  const _Float16* wp0 = WupP + (size_t)(quad * 14) * 128 + col * 8;
  const _Float16* wp1 = WupP + (size_t)((4 + quad) * 14) * 128 + col * 8;
#pragma unroll
  for (int nt = 0; nt < 14; ++nt) {
    h8 bb = *(const h8*)(wp0 + nt * 128);
    acc[nt] = __builtin_amdgcn_mfma_f32_16x16x32_f16(a0, bb, acc[nt], 0, 0, 0);
  }
#pragma unroll
  for (int nt = 0; nt < 14; ++nt) {
    h8 bb = *(const h8*)(wp1 + nt * 128);
    acc[nt] = __builtin_amdgcn_mfma_f32_16x16x32_f16(a1, bb, acc[nt], 0, 0, 0);
  }
  // LDS image: [16 vertices][g*128 + b*32 + c], padded 896->912 elem/row.
  __shared__ _Float16 lds[16 * 912];
#pragma unroll
  for (int nt = 0; nt < 14; ++nt) {
    int gofs = (nt >> 1) * 128 + wv * 32 + (nt & 1) * 16 + col;
#pragma unroll
    for (int r = 0; r < 4; ++r)
      lds[(quad * 4 + r) * 912 + gofs] = (_Float16)acc[nt][r];
  }
  __syncthreads();
  int rem = V1n - v0;
  _Float16* dst = rawq + (size_t)v0 * 896;
#pragma unroll
  for (int i = 0; i < 7; ++i) {
    int m = i * 256 + (int)threadIdx.x;   // h8-chunk index within 16-vertex span
    int vr = m / 112;                     // 112 chunks per vertex row
    int r1 = m - vr * 112;
    if (vr < rem)
      *(h8*)(dst + (size_t)m * 8) = *(const h8*)(lds + vr * 912 + r1 * 8);
  }
}

// ---------------- K2: assemble, batch-fused: thread -> (v, b)
__global__ __launch_bounds__(256) void k_assemble(const float* __restrict__ x2,
    const int* __restrict__ top, const int* __restrict__ down,
    const _Float16* __restrict__ rawq, _Float16* __restrict__ y) {
  int t = blockIdx.x * 256 + threadIdx.x;
  int v = t >> 2, b = t & 3;
  if (v >= V2n) return;
  h8 r0, r1, r2, r3;
  if (v < V1n) {
    int f = top[v];
    const _Float16* src = rawq + ((size_t)f * 4 + b) * 32;
    r0 = *(const h8*)src;        r1 = *(const h8*)(src + 8);
    r2 = *(const h8*)(src + 16); r3 = *(const h8*)(src + 24);
  } else {
    int k = v - V1n;
    int d0 = down[2 * k], d1 = down[2 * k + 1];
    const _Float16* se = rawq + ((size_t)d0 * 4 + b) * 32;
    const _Float16* so = rawq + ((size_t)d1 * 4 + b) * 32;
    h8 a0 = *(const h8*)se,        a1 = *(const h8*)(se + 8);
    h8 a2 = *(const h8*)(se + 16), a3 = *(const h8*)(se + 24);
    h8 c0 = *(const h8*)so,        c1 = *(const h8*)(so + 8);
    h8 c2 = *(const h8*)(so + 16), c3 = *(const h8*)(so + 24);
    __builtin_amdgcn_sched_barrier(0);   // keep all 8 gather loads in flight together
#pragma unroll
    for (int i = 0; i < 4; ++i) {
      r0[i]     = (_Float16)(0.5f * (h2f(a0[2 * i]) + h2f(a0[2 * i + 1])));
      r0[4 + i] = (_Float16)(0.5f * (h2f(a1[2 * i]) + h2f(a1[2 * i + 1])));
      r1[i]     = (_Float16)(0.5f * (h2f(a2[2 * i]) + h2f(a2[2 * i + 1])));
      r1[4 + i] = (_Float16)(0.5f * (h2f(a3[2 * i]) + h2f(a3[2 * i + 1])));
      r2[i]     = (_Float16)(0.5f * (h2f(c0[2 * i]) + h2f(c0[2 * i + 1])));
      r2[4 + i] = (_Float16)(0.5f * (h2f(c1[2 * i]) + h2f(c1[2 * i + 1])));
      r3[i]     = (_Float16)(0.5f * (h2f(c2[2 * i]) + h2f(c2[2 * i + 1])));
      r3[4 + i] = (_Float16)(0.5f * (h2f(c3[2 * i]) + h2f(c3[2 * i + 1])));
    }
  }
  _Float16* dst = y + ((size_t)b * V2n + v) * 64;
  *(h8*)(dst)      = r0; *(h8*)(dst + 8)  = r1;
  *(h8*)(dst + 16) = r2; *(h8*)(dst + 24) = r3;
  const float* xp = x2 + (size_t)b * 32 * V2n + v;
#pragma unroll
  for (int g2 = 0; g2 < 4; ++g2) {
    h8 px;
#pragma unroll
    for (int e = 0; e < 8; ++e) px[e] = (_Float16)xp[(size_t)(g2 * 8 + e) * V2n];
    *(h8*)(dst + 32 + g2 * 8) = px;
  }
}

// ---------------- K2b: pack W1/W2 into fp16 MFMA B-fragment layout (unchanged)
__global__ __launch_bounds__(256) void k_pack(const float* __restrict__ W1,
    const float* __restrict__ W2, _Float16* __restrict__ W1p,
    _Float16* __restrict__ W2p) {
  int i = blockIdx.x * 256 + threadIdx.x;
  if (i < 14336) {
    int e = i & 7, o = (i >> 3) & 31, g = i >> 8;       // g = kt*4+quad
    int k = (g >> 2) * 32 + (g & 3) * 8 + e;
    W1p[i] = (_Float16)W1[o * 448 + k];
  }
  int i2 = i - 14336;
  if (i2 >= 0 && i2 < 7168) {
    int e = i2 & 7, o = (i2 >> 3) & 31, g = i2 >> 8;
    int k = (g >> 2) * 32 + (g & 3) * 8 + e;
    W2p[i2] = (_Float16)W2[o * 224 + k];
  }
}

// ---------------- K3: conv1 + fused BN1-stats; t1 interleaved (V2,B,32)
// Gather cluster is fenced from the MFMA chain so all 14 loads stay in flight
// (VGPR 36 previously => compiler had serialized the gather to ~4-deep MLP).
__global__ __launch_bounds__(256, 4) void k_conv1(const _Float16* __restrict__ y,
    const int* __restrict__ neigh, const _Float16* __restrict__ W1p,
    _Float16* __restrict__ t1, float* __restrict__ sumsR) {
  int b = blockIdx.y;
  int lane = threadIdx.x & 63, wv = threadIdx.x >> 6;
  int col = lane & 15, quad = lane >> 4;
  int v0 = blockIdx.x * 64 + wv * 16;
  int v = v0 + col;
  int vc = min(v, V2n - 1);
  const int* np = neigh + 7 * (size_t)vc;
  int idx[7];
#pragma unroll
  for (int j = 0; j < 7; ++j) idx[j] = np[j];
  const _Float16* yb = y + (size_t)b * V2n * 64 + quad * 8;
  h8 a[14];
#pragma unroll
  for (int j = 0; j < 7; ++j) {
    const _Float16* r = yb + (size_t)idx[j] * 64;
    a[2 * j]     = *(const h8*)r;
    a[2 * j + 1] = *(const h8*)(r + 32);
  }
  __builtin_amdgcn_sched_barrier(0);   // all 14 gathers issued before any MFMA
  f32x4 acc0 = {0.f, 0.f, 0.f, 0.f}, acc1 = {0.f, 0.f, 0.f, 0.f};
  const _Float16* wp = W1p + quad * 256;
#pragma unroll
  for (int kt = 0; kt < 14; ++kt) {
    h8 b0 = *(const h8*)(wp + (size_t)kt * 1024 + col * 8);
    h8 b1 = *(const h8*)(wp + (size_t)kt * 1024 + (16 + col) * 8);
    acc0 = __builtin_amdgcn_mfma_f32_16x16x32_f16(a[kt], b0, acc0, 0, 0, 0);
    acc1 = __builtin_amdgcn_mfma_f32_16x16x32_f16(a[kt], b1, acc1, 0, 0, 0);
  }
  __shared__ _Float16 tile[4][16][32];
  __shared__ float red[4][4][16];
#pragma unroll
  for (int r = 0; r < 4; ++r) {
    tile[wv][quad * 4 + r][col]      = (_Float16)acc0[r];
    tile[wv][quad * 4 + r][16 + col] = (_Float16)acc1[r];
  }
  __syncthreads();
  int row = threadIdx.x >> 2, ch = threadIdx.x & 3;
  int vv = blockIdx.x * 64 + row;
  float s[8], q[8];
#pragma unroll
  for (int e = 0; e < 8; ++e) { s[e] = 0.f; q[e] = 0.f; }
  if (vv < V2n) {
    h8 val = *(const h8*)&tile[row >> 4][row & 15][ch * 8];
    *(h8*)(t1 + ((size_t)vv * 4 + b) * 32 + ch * 8) = val;   // interleaved (V2,B,32)
#pragma unroll
    for (int e = 0; e < 8; ++e) { float x = h2f(val[e]); s[e] = x; q[e] = x * x; }
  }
#pragma unroll
  for (int m = 4; m <= 32; m <<= 1) {
#pragma unroll
    for (int e = 0; e < 8; ++e) { s[e] += __shfl_xor(s[e], m); q[e] += __shfl_xor(q[e], m); }
  }
  if (lane < 4) {
#pragma unroll
    for (int e = 0; e < 8; ++e) { red[wv][lane][e] = s[e]; red[wv][lane][8 + e] = q[e]; }
  }
  __syncthreads();
  if (threadIdx.x < 64) {
    int chh = threadIdx.x >> 4, e = threadIdx.x & 15;
    float v4 = red[0][chh][e] + red[1][chh][e] + red[2][chh][e] + red[3][chh][e];
    int c = chh * 8 + (e & 7);
    int rep = blockIdx.x & 63;
    float* dst = sumsR + rep * 256 + ((e < 8) ? (b * 32 + c) : (128 + b * 32 + c));
    atomicAdd(dst, v4);
  }
}

// ---------------- finalize (unchanged)
__global__ void k_finalize(const float* __restrict__ sumsR, const float* __restrict__ g,
                           const float* __restrict__ be, float* __restrict__ sc,
                           float* __restrict__ sh) {
  int i = threadIdx.x;
  if (i >= 128) return;
  float s = 0.f, q = 0.f;
  for (int r = 0; r < 64; ++r) { s += sumsR[r * 256 + i]; q += sumsR[r * 256 + 128 + i]; }
  float inv = 1.0f / (float)V2n;
  float mu = s * inv;
  float var = fmaf(q, inv, -mu * mu);
  float rs = rsqrtf(var + 1e-5f);
  int o = i & 31;
  float scale = rs * g[o];
  sc[i] = scale;
  sh[i] = fmaf(-mu, scale, be[o]);
}

// ---------------- K5: conv2, batch-fused; reads interleaved t1; writes fp16 t2 (B,32,T2S)
__global__ __launch_bounds__(256, 3) void k_conv2(const _Float16* __restrict__ t1,
    const int* __restrict__ neigh, const _Float16* __restrict__ W2p,
    const float* __restrict__ sc1, const float* __restrict__ sh1,
    _Float16* __restrict__ t2, float* __restrict__ sumsR) {
  int lane = threadIdx.x & 63, wv = threadIdx.x >> 6;
  int col = lane & 15, quad = lane >> 4;
  int v0 = blockIdx.x * 64 + wv * 16;
  int v = v0 + col;
  int vc = min(v, V2n - 1);
  const int* np = neigh + 7 * (size_t)vc;
  int idx[7];
#pragma unroll
  for (int j = 0; j < 7; ++j) idx[j] = np[j];
  float sc[4][8], sh[4][8];
#pragma unroll
  for (int b = 0; b < 4; ++b)
#pragma unroll
    for (int i = 0; i < 8; ++i) {
      sc[b][i] = sc1[b * 32 + quad * 8 + i];
      sh[b][i] = sh1[b * 32 + quad * 8 + i];
    }
  f32x4 acc[4][2];
#pragma unroll
  for (int b = 0; b < 4; ++b) {
    acc[b][0] = (f32x4){0.f, 0.f, 0.f, 0.f};
    acc[b][1] = (f32x4){0.f, 0.f, 0.f, 0.f};
  }
  const _Float16* wp = W2p + quad * 256;
#pragma unroll
  for (int j = 0; j < 7; ++j) {
    const _Float16* r = t1 + (size_t)idx[j] * 128 + quad * 8;
    h8 raws[4];
#pragma unroll
    for (int b = 0; b < 4; ++b) raws[b] = *(const h8*)(r + b * 32);
    __builtin_amdgcn_sched_barrier(0);   // 4-load cluster issues together; j+1 loads may
                                         // still hoist above this j's compute (no fence there)
    h8 w0 = *(const h8*)(wp + (size_t)j * 1024 + col * 8);
    h8 w1 = *(const h8*)(wp + (size_t)j * 1024 + (16 + col) * 8);
#pragma unroll
    for (int b = 0; b < 4; ++b) {
      h8 aa;
#pragma unroll
      for (int e = 0; e < 8; ++e) {
        float f = fmaf(h2f(raws[b][e]), sc[b][e], sh[b][e]);
        f = fmaxf(f, 0.2f * f);
        aa[e] = (_Float16)f;
      }
      acc[b][0] = __builtin_amdgcn_mfma_f32_16x16x32_f16(aa, w0, acc[b][0], 0, 0, 0);
      acc[b][1] = __builtin_amdgcn_mfma_f32_16x16x32_f16(aa, w1, acc[b][1], 0, 0, 0);
    }
  }
  __shared__ float red2[4][16][4];
  int vrow = v0 + quad * 4;
  bool tailblk = (blockIdx.x == gridDim.x - 1);
  int rep = blockIdx.x & 63;
#pragma unroll
  for (int b = 0; b < 4; ++b) {
    if (b) __syncthreads();
    float s0 = 0.f, q0 = 0.f, s1 = 0.f, q1 = 0.f;
    _Float16* tb = t2 + (size_t)b * 32 * T2S;
    if (!tailblk) {
      _Float16* p0 = tb + (size_t)col * T2S + vrow;
      _Float16* p1 = tb + (size_t)(16 + col) * T2S + vrow;
      *(h2*)(p0)     = (h2){(_Float16)acc[b][0][0], (_Float16)acc[b][0][1]};
      *(h2*)(p0 + 2) = (h2){(_Float16)acc[b][0][2], (_Float16)acc[b][0][3]};
      *(h2*)(p1)     = (h2){(_Float16)acc[b][1][0], (_Float16)acc[b][1][1]};
      *(h2*)(p1 + 2) = (h2){(_Float16)acc[b][1][2], (_Float16)acc[b][1][3]};
#pragma unroll
      for (int rr = 0; rr < 4; ++rr) {
        s0 += acc[b][0][rr]; q0 += acc[b][0][rr] * acc[b][0][rr];
        s1 += acc[b][1][rr]; q1 += acc[b][1][rr] * acc[b][1][rr];
      }
    } else {
#pragma unroll
      for (int rr = 0; rr < 4; ++rr) {
        if (vrow + rr < V2n) {
          tb[(size_t)col * T2S + vrow + rr]        = (_Float16)acc[b][0][rr];
          tb[(size_t)(16 + col) * T2S + vrow + rr] = (_Float16)acc[b][1][rr];
          s0 += acc[b][0][rr]; q0 += acc[b][0][rr] * acc[b][0][rr];
          s1 += acc[b][1][rr]; q1 += acc[b][1][rr] * acc[b][1][rr];
        }
      }
    }
#pragma unroll
    for (int m = 16; m <= 32; m <<= 1) {
      s0 += __shfl_xor(s0, m); q0 += __shfl_xor(q0, m);
      s1 += __shfl_xor(s1, m); q1 += __shfl_xor(q1, m);
    }
    if (lane < 16) {
      red2[wv][col][0] = s0; red2[wv][col][1] = q0;
      red2[wv][col][2] = s1; red2[wv][col][3] = q1;
    }
    __syncthreads();
    if (threadIdx.x < 64) {
      int cc = threadIdx.x & 15, which = threadIdx.x >> 4;
      float v4 = red2[0][cc][which] + red2[1][cc][which] +
                 red2[2][cc][which] + red2[3][cc][which];
      int c = (which & 2) ? cc + 16 : cc;
      float* dstp = sumsR + rep * 256 + ((which & 1) ? (128 + b * 32 + c) : (b * 32 + c));
      atomicAdd(dstp, v4);
    }
  }
}

// ---------------- K7: BN2 + LeakyReLU, vectorized: h8 (16B) reads, 4x float2 writes
__global__ __launch_bounds__(256) void k_bnorm(const _Float16* __restrict__ t2,
    const float* __restrict__ sc, const float* __restrict__ sh,
    float* __restrict__ out) {
  int row = blockIdx.y, qrt = blockIdx.x;
  float scale = sc[row], shift = sh[row];
  const _Float16* p = t2 + (size_t)row * T2S;
  float* o = out + (size_t)row * V2n;
  int c0 = qrt * 5120;   // 20480 full h8 chunks over 4 quarters
  for (int cch = c0 + (int)threadIdx.x; cch < c0 + 5120; cch += 256) {
    h8 x = *(const h8*)(p + (size_t)cch * 8);
    float* ob = o + (size_t)cch * 8;
    float f0, f1;
#pragma unroll
    for (int e = 0; e < 4; ++e) {
      f0 = fmaf((float)x[2 * e], scale, shift);     f0 = fmaxf(f0, 0.2f * f0);
      f1 = fmaf((float)x[2 * e + 1], scale, shift); f1 = fmaxf(f1, 0.2f * f1);
      *(float2*)(ob + 2 * e) = make_float2(f0, f1);
    }
  }
  if (qrt == 3 && threadIdx.x < 2) {   // 163842 = 20480*8 + 2 tail
    int i = 163840 + (int)threadIdx.x;
    float a = fmaf((float)p[i], scale, shift);
    o[i] = fmaxf(a, 0.2f * a);
  }
}

extern "C" void kernel_launch(void* const* d_in, const int* in_sizes, int n_in,
                              void* d_out, int out_size, void* d_ws, size_t ws_size,
                              hipStream_t stream) {
  const float* x1   = (const float*)d_in[0];
  const float* x2   = (const float*)d_in[1];
  const int*   neigh= (const int*)d_in[2];
  const int*   top  = (const int*)d_in[3];
  const int*   down = (const int*)d_in[4];
  const float* Wup  = (const float*)d_in[5];
  const float* bup  = (const float*)d_in[6];
  const float* W1   = (const float*)d_in[7];
  // d_in[8] = b1: cancels exactly in BN -> skipped
  const float* g1   = (const float*)d_in[9];
  const float* be1  = (const float*)d_in[10];
  const float* W2   = (const float*)d_in[11];
  // d_in[12] = b2: cancels in BN -> skipped
  const float* g2   = (const float*)d_in[13];
  const float* be2  = (const float*)d_in[14];
  float* out = (float*)d_out;

  char* ws = (char*)d_ws;
  _Float16* rawq = (_Float16*)ws;                         //  73,403,904 B, (V1*7, B, 32), dead after k_assemble
  _Float16* y    = (_Float16*)(ws + 73403904);            //  83,887,104 B, (B, V2, 64)
  _Float16* t1   = (_Float16*)(ws + 157291008);           //  41,943,552 B, (V2, B, 32) interleaved
  float* stats   = (float*)(ws + 199234560);              //   4 KiB (sc/sh only)
  float* sc1 = stats;        float* sh1 = stats + 128;
  float* sc2 = stats + 256;  float* sh2 = stats + 384;
  // Overlays in the rawq region (dead after k_assemble):
  _Float16* WupP = t1;                                     // 28,672 B (t1 written later by conv1)
  _Float16* W1p  = rawq;                                   // 28,672 B
  _Float16* W2p  = rawq + 14336;                           // 14,336 B
  float* sumsR1 = (float*)(ws + (1 << 20));                // 64 reps x 256 f32 = 65,536 B
  float* sumsR2 = (float*)(ws + (1 << 20) + 65536);        // 65,536 B
  _Float16* t2  = (_Float16*)(ws + (2 << 20));             // 41,945,088 B, (B, 32, T2S) fp16, in dead rawq region

  k_pack_up  <<<56, 256, 0, stream>>>(Wup, WupP);
  k_upconv   <<<2561, 256, 0, stream>>>(x1, bup, WupP, rawq);       // 16 vertices x 4 batches/block
  k_assemble <<<2561, 256, 0, stream>>>(x2, top, down, rawq, y);    // batch-fused (v,b) mapping
  k_pack     <<<84, 256, 0, stream>>>(W1, W2, W1p, W2p);   // rawq dead from here
  hipMemsetAsync(sumsR1, 0, 131072, stream);               // zero both replica arrays
  k_conv1    <<<dim3(2561, Bn), 256, 0, stream>>>(y, neigh, W1p, t1, sumsR1);
  k_finalize <<<1, 128, 0, stream>>>(sumsR1, g1, be1, sc1, sh1);
  k_conv2    <<<2561, 256, 0, stream>>>(t1, neigh, W2p, sc1, sh1, t2, sumsR2);  // batch-fused
  k_finalize <<<1, 128, 0, stream>>>(sumsR2, g2, be2, sc2, sh2);
  k_bnorm    <<<dim3(4, 128),   256, 0, stream>>>(t2, sc2, sh2, out);
}

// Round 4
// 447.824 us; speedup vs baseline: 1.0381x; 1.0381x over previous
//
#include <hip/hip_runtime.h>

#define V1n 40962
#define V2n 163842
#define Bn  4
#define T2S 163848   // padded t2 row stride (16B-aligned rows)

typedef _Float16 h8   __attribute__((ext_vector_type(8)));
typedef _Float16 h2   __attribute__((ext_vector_type(2)));
typedef float    f32x4 __attribute__((ext_vector_type(4)));

__device__ __forceinline__ float h2f(_Float16 h) { return (float)h; }

// ---------------- K0: pack Wup into fp16 MFMA B-fragment layout (unchanged)
__global__ __launch_bounds__(256) void k_pack_up(const float* __restrict__ Wup,
                                                 _Float16* __restrict__ WupP) {
  int i = blockIdx.x * 256 + threadIdx.x;
  if (i >= 14336) return;
  int e = i & 7, col = (i >> 3) & 15, g = i >> 7;   // g = (kt*4+quad)*14 + nt
  int nt = g % 14, kq = g / 14;
  int j = nt * 16 + col;
  int k = (kq >> 2) * 32 + (kq & 3) * 8 + e;
  WupP[i] = (_Float16)Wup[j * 64 + k];
}

// ---------------- K1: upconv GEMM. Block = 16 vertices x 4 batches (one wave per batch).
__global__ __launch_bounds__(256, 4) void k_upconv(const float* __restrict__ x1,
    const float* __restrict__ bup, const _Float16* __restrict__ WupP,
    _Float16* __restrict__ rawq) {
  int lane = threadIdx.x & 63, wv = threadIdx.x >> 6;   // wv = batch
  int col = lane & 15, quad = lane >> 4;
  int v0 = blockIdx.x * 16;
  int v = v0 + col;
  int vc = min(v, V1n - 1);
  const float* xb = x1 + ((size_t)wv * 64) * V1n + vc;
  h8 a0, a1;
#pragma unroll
  for (int e = 0; e < 8; ++e) a0[e] = (_Float16)xb[(size_t)(quad * 8 + e) * V1n];
#pragma unroll
  for (int e = 0; e < 8; ++e) a1[e] = (_Float16)xb[(size_t)(32 + quad * 8 + e) * V1n];
  f32x4 acc[14];
#pragma unroll
  for (int nt = 0; nt < 14; ++nt) {
    float bv = bup[nt * 16 + col];
    acc[nt] = (f32x4){bv, bv, bv, bv};
  }
  const _Float16* wp0 = WupP + (size_t)(quad * 14) * 128 + col * 8;
  const _Float16* wp1 = WupP + (size_t)((4 + quad) * 14) * 128 + col * 8;
#pragma unroll
  for (int nt = 0; nt < 14; ++nt) {
    h8 bb = *(const h8*)(wp0 + nt * 128);
    acc[nt] = __builtin_amdgcn_mfma_f32_16x16x32_f16(a0, bb, acc[nt], 0, 0, 0);
  }
#pragma unroll
  for (int nt = 0; nt < 14; ++nt) {
    h8 bb = *(const h8*)(wp1 + nt * 128);
    acc[nt] = __builtin_amdgcn_mfma_f32_16x16x32_f16(a1, bb, acc[nt], 0, 0, 0);
  }
  // LDS image: [16 vertices][g*128 + b*32 + c], padded 896->912 elem/row.
  __shared__ _Float16 lds[16 * 912];
#pragma unroll
  for (int nt = 0; nt < 14; ++nt) {
    int gofs = (nt >> 1) * 128 + wv * 32 + (nt & 1) * 16 + col;
#pragma unroll
    for (int r = 0; r < 4; ++r)
      lds[(quad * 4 + r) * 912 + gofs] = (_Float16)acc[nt][r];
  }
  __syncthreads();
  int rem = V1n - v0;
  _Float16* dst = rawq + (size_t)v0 * 896;
#pragma unroll
  for (int i = 0; i < 7; ++i) {
    int m = i * 256 + (int)threadIdx.x;   // h8-chunk index within 16-vertex span
    int vr = m / 112;                     // 112 chunks per vertex row
    int r1 = m - vr * 112;
    if (vr < rem)
      *(h8*)(dst + (size_t)m * 8) = *(const h8*)(lds + vr * 912 + r1 * 8);
  }
}

// ---------------- K2: assemble, batch-fused: thread -> (v, b)
__global__ __launch_bounds__(256) void k_assemble(const float* __restrict__ x2,
    const int* __restrict__ top, const int* __restrict__ down,
    const _Float16* __restrict__ rawq, _Float16* __restrict__ y) {
  int t = blockIdx.x * 256 + threadIdx.x;
  int v = t >> 2, b = t & 3;
  if (v >= V2n) return;
  h8 r0, r1, r2, r3;
  if (v < V1n) {
    int f = top[v];
    const _Float16* src = rawq + ((size_t)f * 4 + b) * 32;
    r0 = *(const h8*)src;        r1 = *(const h8*)(src + 8);
    r2 = *(const h8*)(src + 16); r3 = *(const h8*)(src + 24);
  } else {
    int k = v - V1n;
    int d0 = down[2 * k], d1 = down[2 * k + 1];
    const _Float16* se = rawq + ((size_t)d0 * 4 + b) * 32;
    const _Float16* so = rawq + ((size_t)d1 * 4 + b) * 32;
    h8 a0 = *(const h8*)se,        a1 = *(const h8*)(se + 8);
    h8 a2 = *(const h8*)(se + 16), a3 = *(const h8*)(se + 24);
    h8 c0 = *(const h8*)so,        c1 = *(const h8*)(so + 8);
    h8 c2 = *(const h8*)(so + 16), c3 = *(const h8*)(so + 24);
#pragma unroll
    for (int i = 0; i < 4; ++i) {
      r0[i]     = (_Float16)(0.5f * (h2f(a0[2 * i]) + h2f(a0[2 * i + 1])));
      r0[4 + i] = (_Float16)(0.5f * (h2f(a1[2 * i]) + h2f(a1[2 * i + 1])));
      r1[i]     = (_Float16)(0.5f * (h2f(a2[2 * i]) + h2f(a2[2 * i + 1])));
      r1[4 + i] = (_Float16)(0.5f * (h2f(a3[2 * i]) + h2f(a3[2 * i + 1])));
      r2[i]     = (_Float16)(0.5f * (h2f(c0[2 * i]) + h2f(c0[2 * i + 1])));
      r2[4 + i] = (_Float16)(0.5f * (h2f(c1[2 * i]) + h2f(c1[2 * i + 1])));
      r3[i]     = (_Float16)(0.5f * (h2f(c2[2 * i]) + h2f(c2[2 * i + 1])));
      r3[4 + i] = (_Float16)(0.5f * (h2f(c3[2 * i]) + h2f(c3[2 * i + 1])));
    }
  }
  _Float16* dst = y + ((size_t)b * V2n + v) * 64;
  *(h8*)(dst)      = r0; *(h8*)(dst + 8)  = r1;
  *(h8*)(dst + 16) = r2; *(h8*)(dst + 24) = r3;
  const float* xp = x2 + (size_t)b * 32 * V2n + v;
#pragma unroll
  for (int g2 = 0; g2 < 4; ++g2) {
    h8 px;
#pragma unroll
    for (int e = 0; e < 8; ++e) px[e] = (_Float16)xp[(size_t)(g2 * 8 + e) * V2n];
    *(h8*)(dst + 32 + g2 * 8) = px;
  }
}

// ---------------- K2b: pack W1/W2 into fp16 MFMA B-fragment layout (unchanged)
__global__ __launch_bounds__(256) void k_pack(const float* __restrict__ W1,
    const float* __restrict__ W2, _Float16* __restrict__ W1p,
    _Float16* __restrict__ W2p) {
  int i = blockIdx.x * 256 + threadIdx.x;
  if (i < 14336) {
    int e = i & 7, o = (i >> 3) & 31, g = i >> 8;       // g = kt*4+quad
    int k = (g >> 2) * 32 + (g & 3) * 8 + e;
    W1p[i] = (_Float16)W1[o * 448 + k];
  }
  int i2 = i - 14336;
  if (i2 >= 0 && i2 < 7168) {
    int e = i2 & 7, o = (i2 >> 3) & 31, g = i2 >> 8;
    int k = (g >> 2) * 32 + (g & 3) * 8 + e;
    W2p[i2] = (_Float16)W2[o * 224 + k];
  }
}

// ---------------- K3: conv1 + fused BN1-stats; t1 interleaved (V2,B,32)
// Gather via inline-asm global_load_dwordx4 with explicit descending vmcnt waits:
// guarantees 14 lines in flight per wave (compiler cannot insert early drains).
// Weights live in LDS so vmcnt counts ONLY gather loads.
__global__ __launch_bounds__(256, 2) void k_conv1(const _Float16* __restrict__ y,
    const int* __restrict__ neigh, const _Float16* __restrict__ W1p,
    _Float16* __restrict__ t1, float* __restrict__ sumsR) {
  __shared__ _Float16 w1s[14336];          // 28 KiB weight copy
  __shared__ _Float16 tile[4][16][32];
  __shared__ float red[4][4][16];
  int b = blockIdx.y;
  int lane = threadIdx.x & 63, wv = threadIdx.x >> 6;
  int col = lane & 15, quad = lane >> 4;
  // stage W1p -> LDS (one-time; drained by the syncthreads below)
#pragma unroll
  for (int i = 0; i < 7; ++i)
    ((h8*)w1s)[i * 256 + (int)threadIdx.x] = ((const h8*)W1p)[i * 256 + (int)threadIdx.x];
  int v0 = blockIdx.x * 64 + wv * 16;
  int v = v0 + col;
  int vc = min(v, V2n - 1);
  const int* np = neigh + 7 * (size_t)vc;
  int idx[7];
#pragma unroll
  for (int j = 0; j < 7; ++j) idx[j] = np[j];
  __syncthreads();                          // drains vmcnt: only gathers outstanding after this
  const _Float16* yb = y + (size_t)b * V2n * 64 + quad * 8;
  h8 a0_0, a1_0, a0_1, a1_1, a0_2, a1_2, a0_3, a1_3, a0_4, a1_4, a0_5, a1_5, a0_6, a1_6;
#define GLD(J, A0v, A1v) { const _Float16* rp = yb + (size_t)idx[J] * 64;            \
  asm volatile("global_load_dwordx4 %0, %2, off\n\t"                                 \
               "global_load_dwordx4 %1, %2, off offset:64"                           \
               : "=&v"(A0v), "=&v"(A1v) : "v"(rp)); }
  GLD(0, a0_0, a1_0) GLD(1, a0_1, a1_1) GLD(2, a0_2, a1_2) GLD(3, a0_3, a1_3)
  GLD(4, a0_4, a1_4) GLD(5, a0_5, a1_5) GLD(6, a0_6, a1_6)
#undef GLD
  f32x4 acc0 = {0.f, 0.f, 0.f, 0.f}, acc1 = {0.f, 0.f, 0.f, 0.f};
  const _Float16* wq = w1s + quad * 256 + col * 8;
#define STEP(J, CNT, A0v, A1v) {                                                     \
  asm volatile("s_waitcnt vmcnt(" CNT ")" : "+v"(A0v), "+v"(A1v));                   \
  h8 b00 = *(const h8*)(wq + (2 * J) * 1024);                                        \
  h8 b01 = *(const h8*)(wq + (2 * J) * 1024 + 128);                                  \
  acc0 = __builtin_amdgcn_mfma_f32_16x16x32_f16(A0v, b00, acc0, 0, 0, 0);            \
  acc1 = __builtin_amdgcn_mfma_f32_16x16x32_f16(A0v, b01, acc1, 0, 0, 0);            \
  h8 b10 = *(const h8*)(wq + (2 * J + 1) * 1024);                                    \
  h8 b11 = *(const h8*)(wq + (2 * J + 1) * 1024 + 128);                              \
  acc0 = __builtin_amdgcn_mfma_f32_16x16x32_f16(A1v, b10, acc0, 0, 0, 0);            \
  acc1 = __builtin_amdgcn_mfma_f32_16x16x32_f16(A1v, b11, acc1, 0, 0, 0); }
  STEP(0, "12", a0_0, a1_0) STEP(1, "10", a0_1, a1_1) STEP(2, "8", a0_2, a1_2)
  STEP(3, "6",  a0_3, a1_3) STEP(4, "4",  a0_4, a1_4) STEP(5, "2", a0_5, a1_5)
  STEP(6, "0",  a0_6, a1_6)
#undef STEP
#pragma unroll
  for (int r = 0; r < 4; ++r) {
    tile[wv][quad * 4 + r][col]      = (_Float16)acc0[r];
    tile[wv][quad * 4 + r][16 + col] = (_Float16)acc1[r];
  }
  __syncthreads();
  int row = threadIdx.x >> 2, ch = threadIdx.x & 3;
  int vv = blockIdx.x * 64 + row;
  float s[8], q[8];
#pragma unroll
  for (int e = 0; e < 8; ++e) { s[e] = 0.f; q[e] = 0.f; }
  if (vv < V2n) {
    h8 val = *(const h8*)&tile[row >> 4][row & 15][ch * 8];
    *(h8*)(t1 + ((size_t)vv * 4 + b) * 32 + ch * 8) = val;   // interleaved (V2,B,32)
#pragma unroll
    for (int e = 0; e < 8; ++e) { float x = h2f(val[e]); s[e] = x; q[e] = x * x; }
  }
#pragma unroll
  for (int m = 4; m <= 32; m <<= 1) {
#pragma unroll
    for (int e = 0; e < 8; ++e) { s[e] += __shfl_xor(s[e], m); q[e] += __shfl_xor(q[e], m); }
  }
  if (lane < 4) {
#pragma unroll
    for (int e = 0; e < 8; ++e) { red[wv][lane][e] = s[e]; red[wv][lane][8 + e] = q[e]; }
  }
  __syncthreads();
  if (threadIdx.x < 64) {
    int chh = threadIdx.x >> 4, e = threadIdx.x & 15;
    float v4 = red[0][chh][e] + red[1][chh][e] + red[2][chh][e] + red[3][chh][e];
    int c = chh * 8 + (e & 7);
    int rep = blockIdx.x & 63;
    float* dst = sumsR + rep * 256 + ((e < 8) ? (b * 32 + c) : (128 + b * 32 + c));
    atomicAdd(dst, v4);
  }
}

// ---------------- finalize (unchanged)
__global__ void k_finalize(const float* __restrict__ sumsR, const float* __restrict__ g,
                           const float* __restrict__ be, float* __restrict__ sc,
                           float* __restrict__ sh) {
  int i = threadIdx.x;
  if (i >= 128) return;
  float s = 0.f, q = 0.f;
  for (int r = 0; r < 64; ++r) { s += sumsR[r * 256 + i]; q += sumsR[r * 256 + 128 + i]; }
  float inv = 1.0f / (float)V2n;
  float mu = s * inv;
  float var = fmaf(q, inv, -mu * mu);
  float rs = rsqrtf(var + 1e-5f);
  int o = i & 31;
  float scale = rs * g[o];
  sc[i] = scale;
  sh[i] = fmaf(-mu, scale, be[o]);
}

// ---------------- K5: conv2, batch-fused; reads interleaved t1; writes fp16 t2 (B,32,T2S)
__global__ __launch_bounds__(256, 3) void k_conv2(const _Float16* __restrict__ t1,
    const int* __restrict__ neigh, const _Float16* __restrict__ W2p,
    const float* __restrict__ sc1, const float* __restrict__ sh1,
    _Float16* __restrict__ t2, float* __restrict__ sumsR) {
  int lane = threadIdx.x & 63, wv = threadIdx.x >> 6;
  int col = lane & 15, quad = lane >> 4;
  int v0 = blockIdx.x * 64 + wv * 16;
  int v = v0 + col;
  int vc = min(v, V2n - 1);
  const int* np = neigh + 7 * (size_t)vc;
  int idx[7];
#pragma unroll
  for (int j = 0; j < 7; ++j) idx[j] = np[j];
  float sc[4][8], sh[4][8];
#pragma unroll
  for (int b = 0; b < 4; ++b)
#pragma unroll
    for (int i = 0; i < 8; ++i) {
      sc[b][i] = sc1[b * 32 + quad * 8 + i];
      sh[b][i] = sh1[b * 32 + quad * 8 + i];
    }
  f32x4 acc[4][2];
#pragma unroll
  for (int b = 0; b < 4; ++b) {
    acc[b][0] = (f32x4){0.f, 0.f, 0.f, 0.f};
    acc[b][1] = (f32x4){0.f, 0.f, 0.f, 0.f};
  }
  const _Float16* wp = W2p + quad * 256;
#pragma unroll
  for (int j = 0; j < 7; ++j) {
    const _Float16* r = t1 + (size_t)idx[j] * 128 + quad * 8;
    h8 raws[4];
#pragma unroll
    for (int b = 0; b < 4; ++b) raws[b] = *(const h8*)(r + b * 32);
    h8 w0 = *(const h8*)(wp + (size_t)j * 1024 + col * 8);
    h8 w1 = *(const h8*)(wp + (size_t)j * 1024 + (16 + col) * 8);
#pragma unroll
    for (int b = 0; b < 4; ++b) {
      h8 aa;
#pragma unroll
      for (int e = 0; e < 8; ++e) {
        float f = fmaf(h2f(raws[b][e]), sc[b][e], sh[b][e]);
        f = fmaxf(f, 0.2f * f);
        aa[e] = (_Float16)f;
      }
      acc[b][0] = __builtin_amdgcn_mfma_f32_16x16x32_f16(aa, w0, acc[b][0], 0, 0, 0);
      acc[b][1] = __builtin_amdgcn_mfma_f32_16x16x32_f16(aa, w1, acc[b][1], 0, 0, 0);
    }
  }
  __shared__ float red2[4][16][4];
  int vrow = v0 + quad * 4;
  bool tailblk = (blockIdx.x == gridDim.x - 1);
  int rep = blockIdx.x & 63;
#pragma unroll
  for (int b = 0; b < 4; ++b) {
    if (b) __syncthreads();
    float s0 = 0.f, q0 = 0.f, s1 = 0.f, q1 = 0.f;
    _Float16* tb = t2 + (size_t)b * 32 * T2S;
    if (!tailblk) {
      _Float16* p0 = tb + (size_t)col * T2S + vrow;
      _Float16* p1 = tb + (size_t)(16 + col) * T2S + vrow;
      *(h2*)(p0)     = (h2){(_Float16)acc[b][0][0], (_Float16)acc[b][0][1]};
      *(h2*)(p0 + 2) = (h2){(_Float16)acc[b][0][2], (_Float16)acc[b][0][3]};
      *(h2*)(p1)     = (h2){(_Float16)acc[b][1][0], (_Float16)acc[b][1][1]};
      *(h2*)(p1 + 2) = (h2){(_Float16)acc[b][1][2], (_Float16)acc[b][1][3]};
#pragma unroll
      for (int rr = 0; rr < 4; ++rr) {
        s0 += acc[b][0][rr]; q0 += acc[b][0][rr] * acc[b][0][rr];
        s1 += acc[b][1][rr]; q1 += acc[b][1][rr] * acc[b][1][rr];
      }
    } else {
#pragma unroll
      for (int rr = 0; rr < 4; ++rr) {
        if (vrow + rr < V2n) {
          tb[(size_t)col * T2S + vrow + rr]        = (_Float16)acc[b][0][rr];
          tb[(size_t)(16 + col) * T2S + vrow + rr] = (_Float16)acc[b][1][rr];
          s0 += acc[b][0][rr]; q0 += acc[b][0][rr] * acc[b][0][rr];
          s1 += acc[b][1][rr]; q1 += acc[b][1][rr] * acc[b][1][rr];
        }
      }
    }
#pragma unroll
    for (int m = 16; m <= 32; m <<= 1) {
      s0 += __shfl_xor(s0, m); q0 += __shfl_xor(q0, m);
      s1 += __shfl_xor(s1, m); q1 += __shfl_xor(q1, m);
    }
    if (lane < 16) {
      red2[wv][col][0] = s0; red2[wv][col][1] = q0;
      red2[wv][col][2] = s1; red2[wv][col][3] = q1;
    }
    __syncthreads();
    if (threadIdx.x < 64) {
      int cc = threadIdx.x & 15, which = threadIdx.x >> 4;
      float v4 = red2[0][cc][which] + red2[1][cc][which] +
                 red2[2][cc][which] + red2[3][cc][which];
      int c = (which & 2) ? cc + 16 : cc;
      float* dstp = sumsR + rep * 256 + ((which & 1) ? (128 + b * 32 + c) : (b * 32 + c));
      atomicAdd(dstp, v4);
    }
  }
}

// ---------------- K7: BN2 + LeakyReLU, vectorized: h8 (16B) reads, 4x float2 writes
__global__ __launch_bounds__(256) void k_bnorm(const _Float16* __restrict__ t2,
    const float* __restrict__ sc, const float* __restrict__ sh,
    float* __restrict__ out) {
  int row = blockIdx.y, qrt = blockIdx.x;
  float scale = sc[row], shift = sh[row];
  const _Float16* p = t2 + (size_t)row * T2S;
  float* o = out + (size_t)row * V2n;
  int c0 = qrt * 5120;   // 20480 full h8 chunks over 4 quarters
  for (int cch = c0 + (int)threadIdx.x; cch < c0 + 5120; cch += 256) {
    h8 x = *(const h8*)(p + (size_t)cch * 8);
    float* ob = o + (size_t)cch * 8;
    float f0, f1;
#pragma unroll
    for (int e = 0; e < 4; ++e) {
      f0 = fmaf((float)x[2 * e], scale, shift);     f0 = fmaxf(f0, 0.2f * f0);
      f1 = fmaf((float)x[2 * e + 1], scale, shift); f1 = fmaxf(f1, 0.2f * f1);
      *(float2*)(ob + 2 * e) = make_float2(f0, f1);
    }
  }
  if (qrt == 3 && threadIdx.x < 2) {   // 163842 = 20480*8 + 2 tail
    int i = 163840 + (int)threadIdx.x;
    float a = fmaf((float)p[i], scale, shift);
    o[i] = fmaxf(a, 0.2f * a);
  }
}

extern "C" void kernel_launch(void* const* d_in, const int* in_sizes, int n_in,
                              void* d_out, int out_size, void* d_ws, size_t ws_size,
                              hipStream_t stream) {
  const float* x1   = (const float*)d_in[0];
  const float* x2   = (const float*)d_in[1];
  const int*   neigh= (const int*)d_in[2];
  const int*   top  = (const int*)d_in[3];
  const int*   down = (const int*)d_in[4];
  const float* Wup  = (const float*)d_in[5];
  const float* bup  = (const float*)d_in[6];
  const float* W1   = (const float*)d_in[7];
  // d_in[8] = b1: cancels exactly in BN -> skipped
  const float* g1   = (const float*)d_in[9];
  const float* be1  = (const float*)d_in[10];
  const float* W2   = (const float*)d_in[11];
  // d_in[12] = b2: cancels in BN -> skipped
  const float* g2   = (const float*)d_in[13];
  const float* be2  = (const float*)d_in[14];
  float* out = (float*)d_out;

  char* ws = (char*)d_ws;
  _Float16* rawq = (_Float16*)ws;                         //  73,403,904 B, (V1*7, B, 32), dead after k_assemble
  _Float16* y    = (_Float16*)(ws + 73403904);            //  83,887,104 B, (B, V2, 64)
  _Float16* t1   = (_Float16*)(ws + 157291008);           //  41,943,552 B, (V2, B, 32) interleaved
  float* stats   = (float*)(ws + 199234560);              //   4 KiB (sc/sh only)
  float* sc1 = stats;        float* sh1 = stats + 128;
  float* sc2 = stats + 256;  float* sh2 = stats + 384;
  // Overlays in the rawq region (dead after k_assemble):
  _Float16* WupP = t1;                                     // 28,672 B (t1 written later by conv1)
  _Float16* W1p  = rawq;                                   // 28,672 B
  _Float16* W2p  = rawq + 14336;                           // 14,336 B
  float* sumsR1 = (float*)(ws + (1 << 20));                // 64 reps x 256 f32 = 65,536 B
  float* sumsR2 = (float*)(ws + (1 << 20) + 65536);        // 65,536 B
  _Float16* t2  = (_Float16*)(ws + (2 << 20));             // 41,945,088 B, (B, 32, T2S) fp16, in dead rawq region

  k_pack_up  <<<56, 256, 0, stream>>>(Wup, WupP);
  k_upconv   <<<2561, 256, 0, stream>>>(x1, bup, WupP, rawq);       // 16 vertices x 4 batches/block
  k_assemble <<<2561, 256, 0, stream>>>(x2, top, down, rawq, y);    // batch-fused (v,b) mapping
  k_pack     <<<84, 256, 0, stream>>>(W1, W2, W1p, W2p);   // rawq dead from here
  hipMemsetAsync(sumsR1, 0, 131072, stream);               // zero both replica arrays
  k_conv1    <<<dim3(2561, Bn), 256, 0, stream>>>(y, neigh, W1p, t1, sumsR1);
  k_finalize <<<1, 128, 0, stream>>>(sumsR1, g1, be1, sc1, sh1);
  k_conv2    <<<2561, 256, 0, stream>>>(t1, neigh, W2p, sc1, sh1, t2, sumsR2);  // batch-fused
  k_finalize <<<1, 128, 0, stream>>>(sumsR2, g2, be2, sc2, sh2);
  k_bnorm    <<<dim3(4, 128),   256, 0, stream>>>(t2, sc2, sh2, out);
}

// Round 5
// 445.629 us; speedup vs baseline: 1.0432x; 1.0049x over previous
//
#include <hip/hip_runtime.h>

#define V1n 40962
#define V2n 163842
#define Bn  4
#define T2S 163848   // padded t2 row stride (16B-aligned rows)

typedef _Float16 h8   __attribute__((ext_vector_type(8)));
typedef _Float16 h2   __attribute__((ext_vector_type(2)));
typedef float    f32x4 __attribute__((ext_vector_type(4)));

__device__ __forceinline__ float h2f(_Float16 h) { return (float)h; }

// ---------------- K0: pack Wup into fp16 MFMA B-fragment layout (unchanged)
__global__ __launch_bounds__(256) void k_pack_up(const float* __restrict__ Wup,
                                                 _Float16* __restrict__ WupP) {
  int i = blockIdx.x * 256 + threadIdx.x;
  if (i >= 14336) return;
  int e = i & 7, col = (i >> 3) & 15, g = i >> 7;   // g = (kt*4+quad)*14 + nt
  int nt = g % 14, kq = g / 14;
  int j = nt * 16 + col;
  int k = (kq >> 2) * 32 + (kq & 3) * 8 + e;
  WupP[i] = (_Float16)Wup[j * 64 + k];
}

// ---------------- K1: upconv GEMM. Block = 16 vertices x 4 batches (one wave per batch).
__global__ __launch_bounds__(256, 4) void k_upconv(const float* __restrict__ x1,
    const float* __restrict__ bup, const _Float16* __restrict__ WupP,
    _Float16* __restrict__ rawq) {
  int lane = threadIdx.x & 63, wv = threadIdx.x >> 6;   // wv = batch
  int col = lane & 15, quad = lane >> 4;
  int v0 = blockIdx.x * 16;
  int v = v0 + col;
  int vc = min(v, V1n - 1);
  const float* xb = x1 + ((size_t)wv * 64) * V1n + vc;
  h8 a0, a1;
#pragma unroll
  for (int e = 0; e < 8; ++e) a0[e] = (_Float16)xb[(size_t)(quad * 8 + e) * V1n];
#pragma unroll
  for (int e = 0; e < 8; ++e) a1[e] = (_Float16)xb[(size_t)(32 + quad * 8 + e) * V1n];
  f32x4 acc[14];
#pragma unroll
  for (int nt = 0; nt < 14; ++nt) {
    float bv = bup[nt * 16 + col];
    acc[nt] = (f32x4){bv, bv, bv, bv};
  }
  const _Float16* wp0 = WupP + (size_t)(quad * 14) * 128 + col * 8;
  const _Float16* wp1 = WupP + (size_t)((4 + quad) * 14) * 128 + col * 8;
#pragma unroll
  for (int nt = 0; nt < 14; ++nt) {
    h8 bb = *(const h8*)(wp0 + nt * 128);
    acc[nt] = __builtin_amdgcn_mfma_f32_16x16x32_f16(a0, bb, acc[nt], 0, 0, 0);
  }
#pragma unroll
  for (int nt = 0; nt < 14; ++nt) {
    h8 bb = *(const h8*)(wp1 + nt * 128);
    acc[nt] = __builtin_amdgcn_mfma_f32_16x16x32_f16(a1, bb, acc[nt], 0, 0, 0);
  }
  // LDS image: [16 vertices][g*128 + b*32 + c], padded 896->912 elem/row.
  __shared__ _Float16 lds[16 * 912];
#pragma unroll
  for (int nt = 0; nt < 14; ++nt) {
    int gofs = (nt >> 1) * 128 + wv * 32 + (nt & 1) * 16 + col;
#pragma unroll
    for (int r = 0; r < 4; ++r)
      lds[(quad * 4 + r) * 912 + gofs] = (_Float16)acc[nt][r];
  }
  __syncthreads();
  int rem = V1n - v0;
  _Float16* dst = rawq + (size_t)v0 * 896;
#pragma unroll
  for (int i = 0; i < 7; ++i) {
    int m = i * 256 + (int)threadIdx.x;   // h8-chunk index within 16-vertex span
    int vr = m / 112;                     // 112 chunks per vertex row
    int r1 = m - vr * 112;
    if (vr < rem)
      *(h8*)(dst + (size_t)m * 8) = *(const h8*)(lds + vr * 912 + r1 * 8);
  }
}

// ---------------- K2: assemble, batch-fused: thread -> (v, b)
__global__ __launch_bounds__(256) void k_assemble(const float* __restrict__ x2,
    const int* __restrict__ top, const int* __restrict__ down,
    const _Float16* __restrict__ rawq, _Float16* __restrict__ y) {
  int t = blockIdx.x * 256 + threadIdx.x;
  int v = t >> 2, b = t & 3;
  if (v >= V2n) return;
  h8 r0, r1, r2, r3;
  if (v < V1n) {
    int f = top[v];
    const _Float16* src = rawq + ((size_t)f * 4 + b) * 32;
    r0 = *(const h8*)src;        r1 = *(const h8*)(src + 8);
    r2 = *(const h8*)(src + 16); r3 = *(const h8*)(src + 24);
  } else {
    int k = v - V1n;
    int d0 = down[2 * k], d1 = down[2 * k + 1];
    const _Float16* se = rawq + ((size_t)d0 * 4 + b) * 32;
    const _Float16* so = rawq + ((size_t)d1 * 4 + b) * 32;
    h8 a0 = *(const h8*)se,        a1 = *(const h8*)(se + 8);
    h8 a2 = *(const h8*)(se + 16), a3 = *(const h8*)(se + 24);
    h8 c0 = *(const h8*)so,        c1 = *(const h8*)(so + 8);
    h8 c2 = *(const h8*)(so + 16), c3 = *(const h8*)(so + 24);
    __builtin_amdgcn_sched_barrier(0);   // keep all 8 gather loads in flight together
#pragma unroll
    for (int i = 0; i < 4; ++i) {
      r0[i]     = (_Float16)(0.5f * (h2f(a0[2 * i]) + h2f(a0[2 * i + 1])));
      r0[4 + i] = (_Float16)(0.5f * (h2f(a1[2 * i]) + h2f(a1[2 * i + 1])));
      r1[i]     = (_Float16)(0.5f * (h2f(a2[2 * i]) + h2f(a2[2 * i + 1])));
      r1[4 + i] = (_Float16)(0.5f * (h2f(a3[2 * i]) + h2f(a3[2 * i + 1])));
      r2[i]     = (_Float16)(0.5f * (h2f(c0[2 * i]) + h2f(c0[2 * i + 1])));
      r2[4 + i] = (_Float16)(0.5f * (h2f(c1[2 * i]) + h2f(c1[2 * i + 1])));
      r3[i]     = (_Float16)(0.5f * (h2f(c2[2 * i]) + h2f(c2[2 * i + 1])));
      r3[4 + i] = (_Float16)(0.5f * (h2f(c3[2 * i]) + h2f(c3[2 * i + 1])));
    }
  }
  _Float16* dst = y + ((size_t)b * V2n + v) * 64;
  *(h8*)(dst)      = r0; *(h8*)(dst + 8)  = r1;
  *(h8*)(dst + 16) = r2; *(h8*)(dst + 24) = r3;
  const float* xp = x2 + (size_t)b * 32 * V2n + v;
#pragma unroll
  for (int g2 = 0; g2 < 4; ++g2) {
    h8 px;
#pragma unroll
    for (int e = 0; e < 8; ++e) px[e] = (_Float16)xp[(size_t)(g2 * 8 + e) * V2n];
    *(h8*)(dst + 32 + g2 * 8) = px;
  }
}

// ---------------- K2b: pack W1/W2, NEW conflict-free LDS-friendly layout:
// W1p[kt*1024 + half*512 + col*32 + quad*8 + e] = W1[(half*16+col)][kt*32+quad*8+e]
// A wave reading (col,quad)-sliced 16B chunks is then fully contiguous (no bank conflict).
__global__ __launch_bounds__(256) void k_pack(const float* __restrict__ W1,
    const float* __restrict__ W2, _Float16* __restrict__ W1p,
    _Float16* __restrict__ W2p) {
  int i = blockIdx.x * 256 + threadIdx.x;
  if (i < 14336) {
    int e = i & 7, quad = (i >> 3) & 3, col = (i >> 5) & 15, half = (i >> 9) & 1, kt = i >> 10;
    int o = half * 16 + col;
    W1p[i] = (_Float16)W1[o * 448 + kt * 32 + quad * 8 + e];
  }
  int i2 = i - 14336;
  if (i2 >= 0 && i2 < 7168) {
    int e = i2 & 7, quad = (i2 >> 3) & 3, col = (i2 >> 5) & 15, half = (i2 >> 9) & 1, j = i2 >> 10;
    int o = half * 16 + col;
    W2p[i2] = (_Float16)W2[o * 224 + j * 32 + quad * 8 + e];
  }
}

// ---------------- K3: conv1 + fused BN1-stats; t1 interleaved (V2,B,32)
// 2-tile rolling pipeline: each wave owns tiles A,B (16 v each). Tile A's 14 gathers are
// issued upfront; each A-step (wait vmcnt(12), 4 MFMA) re-issues the freed register pair
// as tile B's loads -> outstanding stays ~14 through the whole compute phase. All global
// stores happen after vmcnt reaches 0, keeping the count discipline pure.
__global__ __launch_bounds__(256, 4) void k_conv1(const _Float16* __restrict__ y,
    const int* __restrict__ neigh, const _Float16* __restrict__ W1p,
    _Float16* __restrict__ t1, float* __restrict__ sumsR) {
  __shared__ _Float16 w1s[14336];          // 28 KiB weight copy (linear, conflict-free layout)
  __shared__ _Float16 tile[8][16][32];     // 8 KiB
  __shared__ float red[4][4][16];          // 1 KiB
  int b = blockIdx.y;
  int tid = threadIdx.x;
  int lane = tid & 63, wv = tid >> 6;
  int col = lane & 15, quad = lane >> 4;
#pragma unroll
  for (int i = 0; i < 7; ++i)
    ((h8*)w1s)[i * 256 + tid] = ((const h8*)W1p)[i * 256 + tid];
  int v0 = blockIdx.x * 128 + wv * 32;
  int vA = v0 + col, vB = v0 + 16 + col;
  int vcA = min(vA, V2n - 1), vcB = min(vB, V2n - 1);
  const int* npA = neigh + 7 * (size_t)vcA;
  const int* npB = neigh + 7 * (size_t)vcB;
  int idxA[7], idxB[7];
#pragma unroll
  for (int j = 0; j < 7; ++j) { idxA[j] = npA[j]; idxB[j] = npB[j]; }
  __syncthreads();                          // drains ALL vmem: only asm gathers outstanding after
  const _Float16* yb = y + (size_t)b * V2n * 64 + quad * 8;
  h8 P0, P1, P2, P3, P4, P5, P6, P7, P8, P9, P10, P11, P12, P13;
#define GA(J, RA, RB) { const _Float16* rp = yb + (size_t)idxA[J] * 64;              \
  asm volatile("global_load_dwordx4 %0, %2, off\n\t"                                 \
               "global_load_dwordx4 %1, %2, off offset:64"                           \
               : "=&v"(RA), "=&v"(RB) : "v"(rp)); }
  GA(0, P0, P1) GA(1, P2, P3) GA(2, P4, P5) GA(3, P6, P7)
  GA(4, P8, P9) GA(5, P10, P11) GA(6, P12, P13)
#undef GA
  f32x4 accA0 = {0.f, 0.f, 0.f, 0.f}, accA1 = {0.f, 0.f, 0.f, 0.f};
  const _Float16* wq = w1s + col * 32 + quad * 8;
#define STEPA(J, RA, RB) {                                                           \
  asm volatile("s_waitcnt vmcnt(12)" : "+v"(RA), "+v"(RB));                          \
  h8 b00 = *(const h8*)(wq + (2 * J) * 1024);                                        \
  h8 b01 = *(const h8*)(wq + (2 * J) * 1024 + 512);                                  \
  accA0 = __builtin_amdgcn_mfma_f32_16x16x32_f16(RA, b00, accA0, 0, 0, 0);           \
  accA1 = __builtin_amdgcn_mfma_f32_16x16x32_f16(RA, b01, accA1, 0, 0, 0);           \
  h8 b10 = *(const h8*)(wq + (2 * J) * 1024 + 1024);                                 \
  h8 b11 = *(const h8*)(wq + (2 * J) * 1024 + 1536);                                 \
  accA0 = __builtin_amdgcn_mfma_f32_16x16x32_f16(RB, b10, accA0, 0, 0, 0);           \
  accA1 = __builtin_amdgcn_mfma_f32_16x16x32_f16(RB, b11, accA1, 0, 0, 0);           \
  const _Float16* rp = yb + (size_t)idxB[J] * 64;                                    \
  asm volatile("global_load_dwordx4 %0, %2, off\n\t"                                 \
               "global_load_dwordx4 %1, %2, off offset:64"                           \
               : "=&v"(RA), "=&v"(RB) : "v"(rp)); }
  STEPA(0, P0, P1) STEPA(1, P2, P3) STEPA(2, P4, P5) STEPA(3, P6, P7)
  STEPA(4, P8, P9) STEPA(5, P10, P11) STEPA(6, P12, P13)
#undef STEPA
  f32x4 accB0 = {0.f, 0.f, 0.f, 0.f}, accB1 = {0.f, 0.f, 0.f, 0.f};
#define STEPB(J, CNT, RA, RB) {                                                      \
  asm volatile("s_waitcnt vmcnt(" CNT ")" : "+v"(RA), "+v"(RB));                     \
  h8 b00 = *(const h8*)(wq + (2 * J) * 1024);                                        \
  h8 b01 = *(const h8*)(wq + (2 * J) * 1024 + 512);                                  \
  accB0 = __builtin_amdgcn_mfma_f32_16x16x32_f16(RA, b00, accB0, 0, 0, 0);           \
  accB1 = __builtin_amdgcn_mfma_f32_16x16x32_f16(RA, b01, accB1, 0, 0, 0);           \
  h8 b10 = *(const h8*)(wq + (2 * J) * 1024 + 1024);                                 \
  h8 b11 = *(const h8*)(wq + (2 * J) * 1024 + 1536);                                 \
  accB0 = __builtin_amdgcn_mfma_f32_16x16x32_f16(RB, b10, accB0, 0, 0, 0);           \
  accB1 = __builtin_amdgcn_mfma_f32_16x16x32_f16(RB, b11, accB1, 0, 0, 0); }
  STEPB(0, "12", P0, P1) STEPB(1, "10", P2, P3) STEPB(2, "8", P4, P5)
  STEPB(3, "6",  P6, P7) STEPB(4, "4",  P8, P9) STEPB(5, "2", P10, P11)
  STEPB(6, "0",  P12, P13)
#undef STEPB
  // epilogue: both tiles -> LDS transpose image
#pragma unroll
  for (int r = 0; r < 4; ++r) {
    tile[wv * 2][quad * 4 + r][col]          = (_Float16)accA0[r];
    tile[wv * 2][quad * 4 + r][16 + col]     = (_Float16)accA1[r];
    tile[wv * 2 + 1][quad * 4 + r][col]      = (_Float16)accB0[r];
    tile[wv * 2 + 1][quad * 4 + r][16 + col] = (_Float16)accB1[r];
  }
  __syncthreads();
  int row = tid >> 2, ch = tid & 3;
  float s[8], q[8];
#pragma unroll
  for (int e = 0; e < 8; ++e) { s[e] = 0.f; q[e] = 0.f; }
#pragma unroll
  for (int h = 0; h < 2; ++h) {
    int r128 = h * 64 + row;
    int vv = blockIdx.x * 128 + r128;
    if (vv < V2n) {
      h8 val = *(const h8*)&tile[r128 >> 4][r128 & 15][ch * 8];
      *(h8*)(t1 + ((size_t)vv * 4 + b) * 32 + ch * 8) = val;   // interleaved (V2,B,32)
#pragma unroll
      for (int e = 0; e < 8; ++e) { float x = h2f(val[e]); s[e] += x; q[e] += x * x; }
    }
  }
#pragma unroll
  for (int m = 4; m <= 32; m <<= 1) {
#pragma unroll
    for (int e = 0; e < 8; ++e) { s[e] += __shfl_xor(s[e], m); q[e] += __shfl_xor(q[e], m); }
  }
  if (lane < 4) {
#pragma unroll
    for (int e = 0; e < 8; ++e) { red[wv][lane][e] = s[e]; red[wv][lane][8 + e] = q[e]; }
  }
  __syncthreads();
  if (tid < 64) {
    int chh = tid >> 4, e = tid & 15;
    float v4 = red[0][chh][e] + red[1][chh][e] + red[2][chh][e] + red[3][chh][e];
    int c = chh * 8 + (e & 7);
    int rep = blockIdx.x & 63;
    float* dst = sumsR + rep * 256 + ((e < 8) ? (b * 32 + c) : (128 + b * 32 + c));
    atomicAdd(dst, v4);
  }
}

// ---------------- finalize (unchanged)
__global__ void k_finalize(const float* __restrict__ sumsR, const float* __restrict__ g,
                           const float* __restrict__ be, float* __restrict__ sc,
                           float* __restrict__ sh) {
  int i = threadIdx.x;
  if (i >= 128) return;
  float s = 0.f, q = 0.f;
  for (int r = 0; r < 64; ++r) { s += sumsR[r * 256 + i]; q += sumsR[r * 256 + 128 + i]; }
  float inv = 1.0f / (float)V2n;
  float mu = s * inv;
  float var = fmaf(q, inv, -mu * mu);
  float rs = rsqrtf(var + 1e-5f);
  int o = i & 31;
  float scale = rs * g[o];
  sc[i] = scale;
  sh[i] = fmaf(-mu, scale, be[o]);
}

// ---------------- K5: conv2, batch-per-wave. Block = 16 vertices x 4 waves (wave = batch).
// Weights in LDS (vmcnt stays pure), 7 asm gathers issued upfront, descending waits.
__global__ __launch_bounds__(256, 4) void k_conv2(const _Float16* __restrict__ t1,
    const int* __restrict__ neigh, const _Float16* __restrict__ W2p,
    const float* __restrict__ sc1, const float* __restrict__ sh1,
    _Float16* __restrict__ t2, float* __restrict__ sumsR) {
  __shared__ _Float16 w2s[7168];           // 14 KiB
  int tid = threadIdx.x;
  int lane = tid & 63, b = tid >> 6;       // wave index = batch
  int col = lane & 15, quad = lane >> 4;
  for (int i = tid; i < 896; i += 256)
    ((h8*)w2s)[i] = ((const h8*)W2p)[i];
  int v0 = blockIdx.x * 16;
  int v = v0 + col, vc = min(v, V2n - 1);
  const int* np = neigh + 7 * (size_t)vc;
  int idx0 = np[0], idx1 = np[1], idx2 = np[2], idx3 = np[3],
      idx4 = np[4], idx5 = np[5], idx6 = np[6];
  float sc_[8], sh_[8];
#pragma unroll
  for (int i = 0; i < 8; ++i) {
    sc_[i] = sc1[b * 32 + quad * 8 + i];
    sh_[i] = sh1[b * 32 + quad * 8 + i];
  }
  __syncthreads();                          // drains ALL vmem (weights, idx, sc/sh)
  const _Float16* t1b = t1 + b * 32 + quad * 8;
  h8 P0, P1, P2, P3, P4, P5, P6;
#define G2(IDX, R) { const _Float16* rp = t1b + (size_t)(IDX) * 128;                 \
  asm volatile("global_load_dwordx4 %0, %1, off" : "=&v"(R) : "v"(rp)); }
  G2(idx0, P0) G2(idx1, P1) G2(idx2, P2) G2(idx3, P3)
  G2(idx4, P4) G2(idx5, P5) G2(idx6, P6)
#undef G2
  f32x4 acc0 = {0.f, 0.f, 0.f, 0.f}, acc1 = {0.f, 0.f, 0.f, 0.f};
  const _Float16* wq = w2s + col * 32 + quad * 8;
#define S2(J, CNT, R) {                                                              \
  asm volatile("s_waitcnt vmcnt(" CNT ")" : "+v"(R));                                \
  h8 aa;                                                                             \
  _Pragma("unroll")                                                                  \
  for (int e = 0; e < 8; ++e) {                                                      \
    float f = fmaf(h2f(R[e]), sc_[e], sh_[e]);                                       \
    f = fmaxf(f, 0.2f * f);                                                          \
    aa[e] = (_Float16)f;                                                             \
  }                                                                                  \
  h8 w0 = *(const h8*)(wq + J * 1024);                                               \
  h8 w1 = *(const h8*)(wq + J * 1024 + 512);                                         \
  acc0 = __builtin_amdgcn_mfma_f32_16x16x32_f16(aa, w0, acc0, 0, 0, 0);              \
  acc1 = __builtin_amdgcn_mfma_f32_16x16x32_f16(aa, w1, acc1, 0, 0, 0); }
  S2(0, "6", P0) S2(1, "5", P1) S2(2, "4", P2) S2(3, "3", P3)
  S2(4, "2", P4) S2(5, "1", P5) S2(6, "0", P6)
#undef S2
  // epilogue: t2 stores + BN2 stats
  int vrow = v0 + quad * 4;
  float s0 = 0.f, q0 = 0.f, s1 = 0.f, q1 = 0.f;
  _Float16* tb = t2 + (size_t)b * 32 * T2S;
  if (blockIdx.x != gridDim.x - 1) {
    _Float16* p0 = tb + (size_t)col * T2S + vrow;
    _Float16* p1 = tb + (size_t)(16 + col) * T2S + vrow;
    *(h2*)(p0)     = (h2){(_Float16)acc0[0], (_Float16)acc0[1]};
    *(h2*)(p0 + 2) = (h2){(_Float16)acc0[2], (_Float16)acc0[3]};
    *(h2*)(p1)     = (h2){(_Float16)acc1[0], (_Float16)acc1[1]};
    *(h2*)(p1 + 2) = (h2){(_Float16)acc1[2], (_Float16)acc1[3]};
#pragma unroll
    for (int rr = 0; rr < 4; ++rr) {
      s0 += acc0[rr]; q0 += acc0[rr] * acc0[rr];
      s1 += acc1[rr]; q1 += acc1[rr] * acc1[rr];
    }
  } else {
#pragma unroll
    for (int rr = 0; rr < 4; ++rr) {
      if (vrow + rr < V2n) {
        tb[(size_t)col * T2S + vrow + rr]        = (_Float16)acc0[rr];
        tb[(size_t)(16 + col) * T2S + vrow + rr] = (_Float16)acc1[rr];
        s0 += acc0[rr]; q0 += acc0[rr] * acc0[rr];
        s1 += acc1[rr]; q1 += acc1[rr] * acc1[rr];
      }
    }
  }
#pragma unroll
  for (int m = 16; m <= 32; m <<= 1) {
    s0 += __shfl_xor(s0, m); q0 += __shfl_xor(q0, m);
    s1 += __shfl_xor(s1, m); q1 += __shfl_xor(q1, m);
  }
  if (lane < 16) {
    int rep = blockIdx.x & 63;
    float* base = sumsR + rep * 256;
    atomicAdd(base + b * 32 + col, s0);
    atomicAdd(base + b * 32 + 16 + col, s1);
    atomicAdd(base + 128 + b * 32 + col, q0);
    atomicAdd(base + 128 + b * 32 + 16 + col, q1);
  }
}

// ---------------- K7: BN2 + LeakyReLU, vectorized: h8 (16B) reads, 4x float2 writes
__global__ __launch_bounds__(256) void k_bnorm(const _Float16* __restrict__ t2,
    const float* __restrict__ sc, const float* __restrict__ sh,
    float* __restrict__ out) {
  int row = blockIdx.y, qrt = blockIdx.x;
  float scale = sc[row], shift = sh[row];
  const _Float16* p = t2 + (size_t)row * T2S;
  float* o = out + (size_t)row * V2n;
  int c0 = qrt * 5120;   // 20480 full h8 chunks over 4 quarters
  for (int cch = c0 + (int)threadIdx.x; cch < c0 + 5120; cch += 256) {
    h8 x = *(const h8*)(p + (size_t)cch * 8);
    float* ob = o + (size_t)cch * 8;
    float f0, f1;
#pragma unroll
    for (int e = 0; e < 4; ++e) {
      f0 = fmaf((float)x[2 * e], scale, shift);     f0 = fmaxf(f0, 0.2f * f0);
      f1 = fmaf((float)x[2 * e + 1], scale, shift); f1 = fmaxf(f1, 0.2f * f1);
      *(float2*)(ob + 2 * e) = make_float2(f0, f1);
    }
  }
  if (qrt == 3 && threadIdx.x < 2) {   // 163842 = 20480*8 + 2 tail
    int i = 163840 + (int)threadIdx.x;
    float a = fmaf((float)p[i], scale, shift);
    o[i] = fmaxf(a, 0.2f * a);
  }
}

extern "C" void kernel_launch(void* const* d_in, const int* in_sizes, int n_in,
                              void* d_out, int out_size, void* d_ws, size_t ws_size,
                              hipStream_t stream) {
  const float* x1   = (const float*)d_in[0];
  const float* x2   = (const float*)d_in[1];
  const int*   neigh= (const int*)d_in[2];
  const int*   top  = (const int*)d_in[3];
  const int*   down = (const int*)d_in[4];
  const float* Wup  = (const float*)d_in[5];
  const float* bup  = (const float*)d_in[6];
  const float* W1   = (const float*)d_in[7];
  // d_in[8] = b1: cancels exactly in BN -> skipped
  const float* g1   = (const float*)d_in[9];
  const float* be1  = (const float*)d_in[10];
  const float* W2   = (const float*)d_in[11];
  // d_in[12] = b2: cancels in BN -> skipped
  const float* g2   = (const float*)d_in[13];
  const float* be2  = (const float*)d_in[14];
  float* out = (float*)d_out;

  char* ws = (char*)d_ws;
  _Float16* rawq = (_Float16*)ws;                         //  73,403,904 B, (V1*7, B, 32), dead after k_assemble
  _Float16* y    = (_Float16*)(ws + 73403904);            //  83,887,104 B, (B, V2, 64)
  _Float16* t1   = (_Float16*)(ws + 157291008);           //  41,943,552 B, (V2, B, 32) interleaved
  float* stats   = (float*)(ws + 199234560);              //   4 KiB (sc/sh only)
  float* sc1 = stats;        float* sh1 = stats + 128;
  float* sc2 = stats + 256;  float* sh2 = stats + 384;
  // Overlays in the rawq region (dead after k_assemble):
  _Float16* WupP = t1;                                     // 28,672 B (t1 written later by conv1)
  _Float16* W1p  = rawq;                                   // 28,672 B
  _Float16* W2p  = rawq + 14336;                           // 14,336 B
  float* sumsR1 = (float*)(ws + (1 << 20));                // 64 reps x 256 f32 = 65,536 B
  float* sumsR2 = (float*)(ws + (1 << 20) + 65536);        // 65,536 B
  _Float16* t2  = (_Float16*)(ws + (2 << 20));             // 41,945,088 B, (B, 32, T2S) fp16, in dead rawq region

  k_pack_up  <<<56, 256, 0, stream>>>(Wup, WupP);
  k_upconv   <<<2561, 256, 0, stream>>>(x1, bup, WupP, rawq);       // 16 vertices x 4 batches/block
  k_assemble <<<2561, 256, 0, stream>>>(x2, top, down, rawq, y);    // batch-fused (v,b) mapping
  k_pack     <<<84, 256, 0, stream>>>(W1, W2, W1p, W2p);   // rawq dead from here
  hipMemsetAsync(sumsR1, 0, 131072, stream);               // zero both replica arrays
  k_conv1    <<<dim3(1281, Bn), 256, 0, stream>>>(y, neigh, W1p, t1, sumsR1);
  k_finalize <<<1, 128, 0, stream>>>(sumsR1, g1, be1, sc1, sh1);
  k_conv2    <<<10241, 256, 0, stream>>>(t1, neigh, W2p, sc1, sh1, t2, sumsR2);  // batch-per-wave
  k_finalize <<<1, 128, 0, stream>>>(sumsR2, g2, be2, sc2, sh2);
  k_bnorm    <<<dim3(4, 128),   256, 0, stream>>>(t2, sc2, sh2, out);
}